// Round 2
// baseline (1766.899 us; speedup 1.0000x reference)
//
#include <hip/hip_runtime.h>

#define NN 100000
#define CC 256
#define EE 3200000

__device__ __forceinline__ float4 f4add(float4 a, float4 b) {
  return make_float4(a.x + b.x, a.y + b.y, a.z + b.z, a.w + b.w);
}

// ---- degree histogram (incoming edges; +1 self-loop added analytically later) ----
__global__ void k_deg(const int* __restrict__ dst, int* __restrict__ cnt, int n) {
  int i = blockIdx.x * blockDim.x + threadIdx.x;
  int stride = gridDim.x * blockDim.x;
  for (; i < n; i += stride) {
    unsigned d = (unsigned)dst[i];
    if (d < NN) atomicAdd(&cnt[d], 1);
  }
}

__global__ void k_dis(const int* __restrict__ cnt, float* __restrict__ dis, int n) {
  int i = blockIdx.x * blockDim.x + threadIdx.x;
  if (i < n) dis[i] = 1.0f / sqrtf((float)(cnt[i] + 1));
}

// ---- exclusive scan over cnt -> offs (single block, 1024 threads) ----
__global__ void k_scan(const int* __restrict__ cnt, int* __restrict__ offs, int n) {
  __shared__ int wsum[16];
  __shared__ int carry_s;
  int t = threadIdx.x;
  int lane = t & 63, wv = t >> 6;
  if (t == 0) carry_s = 0;
  __syncthreads();
  for (int base = 0; base < n; base += 1024) {
    int idx = base + t;
    int v = (idx < n) ? cnt[idx] : 0;
    int x = v;
#pragma unroll
    for (int d = 1; d < 64; d <<= 1) {
      int y = __shfl_up(x, d, 64);
      if (lane >= d) x += y;
    }
    if (lane == 63) wsum[wv] = x;
    __syncthreads();
    int wpre = 0, total = 0;
#pragma unroll
    for (int w = 0; w < 16; ++w) {
      int s = wsum[w];
      if (w < wv) wpre += s;
      total += s;
    }
    int carry = carry_s;
    if (idx < n) offs[idx] = carry + wpre + x - v;
    __syncthreads();
    if (t == 0) carry_s = carry + total;
    __syncthreads();
  }
  if (t == 0) offs[n] = carry_s;
}

// ---- scatter edge src indices into CSR slots ----
__global__ void k_scatter(const int* __restrict__ src, const int* __restrict__ dst,
                          const int* __restrict__ offs, int* __restrict__ fill,
                          int* __restrict__ csr, int n) {
  int i = blockIdx.x * blockDim.x + threadIdx.x;
  int stride = gridDim.x * blockDim.x;
  for (; i < n; i += stride) {
    unsigned d = (unsigned)dst[i];
    unsigned s = (unsigned)src[i];
    if (d < NN && s < NN) {
      int p = offs[d] + atomicAdd(&fill[d], 1);
      csr[p] = (int)s;
    }
  }
}

// ---- fp32 GEMM: Out[m][c] = dis[m] * sum_k A[m][k] * W[k][c] ----
#define TM 128
#define TN 128
#define KB 16
#define AS_LD 132  // (132*4)%128==16 -> breaks 32-bank pow2 stride; rows stay 16B aligned

__global__ __launch_bounds__(256) void k_gemm_scale(
    const float* __restrict__ A, const float* __restrict__ W,
    const float* __restrict__ dis, float* __restrict__ Out, int M) {
  __shared__ float As[KB * AS_LD];  // [k][m]
  __shared__ float Bs[KB * TN];     // [k][c]
  const int tid = threadIdx.x;
  const int tx = tid & 15, ty = tid >> 4;
  const int row0 = blockIdx.x * TM;
  const int col0 = blockIdx.y * TN;
  float acc[8][8] = {};

  for (int k0 = 0; k0 < CC; k0 += KB) {
    // A tile: 128 rows x KB, stored transposed As[k][m]
#pragma unroll
    for (int l = tid; l < TM * KB / 4; l += 256) {
      int r = l >> 2;
      int kq = (l & 3) << 2;
      int grow = row0 + r;
      float4 v = make_float4(0.f, 0.f, 0.f, 0.f);
      if (grow < M) v = *(const float4*)&A[(size_t)grow * CC + k0 + kq];
      As[(kq + 0) * AS_LD + r] = v.x;
      As[(kq + 1) * AS_LD + r] = v.y;
      As[(kq + 2) * AS_LD + r] = v.z;
      As[(kq + 3) * AS_LD + r] = v.w;
    }
    // B tile: KB x 128
#pragma unroll
    for (int l = tid; l < KB * TN / 4; l += 256) {
      int kk = l >> 5;
      int cq = (l & 31) << 2;
      *(float4*)&Bs[kk * TN + cq] =
          *(const float4*)&W[(size_t)(k0 + kk) * CC + col0 + cq];
    }
    __syncthreads();
#pragma unroll
    for (int k = 0; k < KB; ++k) {
      float4 a0 = *(const float4*)&As[k * AS_LD + ty * 4];
      float4 a1 = *(const float4*)&As[k * AS_LD + 64 + ty * 4];
      float4 b0 = *(const float4*)&Bs[k * TN + tx * 4];
      float4 b1 = *(const float4*)&Bs[k * TN + 64 + tx * 4];
      float a[8] = {a0.x, a0.y, a0.z, a0.w, a1.x, a1.y, a1.z, a1.w};
      float b[8] = {b0.x, b0.y, b0.z, b0.w, b1.x, b1.y, b1.z, b1.w};
#pragma unroll
      for (int i = 0; i < 8; ++i)
#pragma unroll
        for (int j = 0; j < 8; ++j)
          acc[i][j] += a[i] * b[j];
    }
    __syncthreads();
  }

#pragma unroll
  for (int i = 0; i < 8; ++i) {
    int r = row0 + (i < 4 ? ty * 4 + i : 64 + ty * 4 + (i - 4));
    if (r < M) {
      float sc = dis[r];
      float4 v0 = make_float4(acc[i][0] * sc, acc[i][1] * sc, acc[i][2] * sc, acc[i][3] * sc);
      float4 v1 = make_float4(acc[i][4] * sc, acc[i][5] * sc, acc[i][6] * sc, acc[i][7] * sc);
      float* o = &Out[(size_t)r * CC + col0 + tx * 4];
      *(float4*)o = v0;
      *(float4*)(o + 64) = v1;
    }
  }
}

// ---- CSR aggregation: out[i] = relu(dis[i]*(sum_{e in(i)} hs[src_e] + hs[i]) + b) ----
__global__ __launch_bounds__(256) void k_aggregate(
    const float* __restrict__ hs, const int* __restrict__ offs,
    const int* __restrict__ csr, const float* __restrict__ dis,
    const float* __restrict__ bias, float* __restrict__ out, int n) {
  int node = blockIdx.x * 4 + (threadIdx.x >> 6);
  if (node >= n) return;
  int lane = threadIdx.x & 63;
  int c4 = lane << 2;
  int beg = offs[node], end = offs[node + 1];
  float4 a0 = *(const float4*)&hs[(size_t)node * CC + c4];  // self-loop term
  float4 a1 = make_float4(0.f, 0.f, 0.f, 0.f);
  int e = beg;
  for (; e + 2 <= end; e += 2) {
    int s0 = csr[e], s1 = csr[e + 1];
    float4 v0 = *(const float4*)&hs[(size_t)s0 * CC + c4];
    float4 v1 = *(const float4*)&hs[(size_t)s1 * CC + c4];
    a0 = f4add(a0, v0);
    a1 = f4add(a1, v1);
  }
  if (e < end) {
    int s0 = csr[e];
    a0 = f4add(a0, *(const float4*)&hs[(size_t)s0 * CC + c4]);
  }
  float4 acc = f4add(a0, a1);
  float sc = dis[node];
  float4 bv = *(const float4*)&bias[c4];
  float4 r;
  r.x = fmaxf(acc.x * sc + bv.x, 0.f);
  r.y = fmaxf(acc.y * sc + bv.y, 0.f);
  r.z = fmaxf(acc.z * sc + bv.z, 0.f);
  r.w = fmaxf(acc.w * sc + bv.w, 0.f);
  *(float4*)&out[(size_t)node * CC + c4] = r;
}

// ---- final projection: out[i] = h2[i] . Wl + bl ----
__global__ __launch_bounds__(256) void k_final(
    const float* __restrict__ h, const float* __restrict__ Wl,
    const float* __restrict__ bl, float* __restrict__ out, int n) {
  int node = blockIdx.x * 4 + (threadIdx.x >> 6);
  if (node >= n) return;
  int lane = threadIdx.x & 63;
  float4 a = *(const float4*)&h[(size_t)node * CC + (lane << 2)];
  float4 w = *(const float4*)&Wl[lane << 2];
  float s = a.x * w.x + a.y * w.y + a.z * w.z + a.w * w.w;
#pragma unroll
  for (int d = 32; d > 0; d >>= 1) s += __shfl_down(s, d, 64);
  if (lane == 0) out[node] = s + bl[0];
}

extern "C" void kernel_launch(void* const* d_in, const int* in_sizes, int n_in,
                              void* d_out, int out_size, void* d_ws, size_t ws_size,
                              hipStream_t stream) {
  const float* x = (const float*)d_in[0];
  const int* ei = (const int*)d_in[1];  // harness delivers integer inputs as int32
  const float* W1 = (const float*)d_in[2];
  const float* b1 = (const float*)d_in[3];
  const float* W2 = (const float*)d_in[4];
  const float* b2 = (const float*)d_in[5];
  const float* Wl = (const float*)d_in[6];
  const float* bl = (const float*)d_in[7];
  float* out = (float*)d_out;

  const int* src = ei;
  const int* dst = ei + EE;

  char* ws = (char*)d_ws;
  size_t off = 0;
  auto alloc = [&](size_t bytes) {
    char* p = ws + off;
    off = (off + bytes + 255) & ~(size_t)255;
    return p;
  };
  float* dis = (float*)alloc((size_t)NN * 4);
  int* cnt = (int*)alloc((size_t)NN * 4);   // reused as `fill` during scatter
  int* offs = (int*)alloc((size_t)(NN + 1) * 4);
  int* csr = (int*)alloc((size_t)EE * 4);
  float* bufA = (float*)alloc((size_t)NN * CC * 4);  // hs (scaled GEMM out)
  float* bufB = (float*)alloc((size_t)NN * CC * 4);  // h1 / h2

  hipMemsetAsync(cnt, 0, (size_t)NN * 4, stream);

  k_deg<<<2048, 256, 0, stream>>>(dst, cnt, EE);
  k_dis<<<(NN + 255) / 256, 256, 0, stream>>>(cnt, dis, NN);
  k_scan<<<1, 1024, 0, stream>>>(cnt, offs, NN);
  // cnt is dead now (deg folded into dis/offs) -> reuse as fill counters
  hipMemsetAsync(cnt, 0, (size_t)NN * 4, stream);
  k_scatter<<<2048, 256, 0, stream>>>(src, dst, offs, cnt, csr, EE);

  dim3 ggrid((NN + TM - 1) / TM, CC / TN);
  // layer 1: hs = (x @ W1) * dis[row]; h1 = relu(dis*(agg+self) + b1)
  k_gemm_scale<<<ggrid, 256, 0, stream>>>(x, W1, dis, bufA, NN);
  k_aggregate<<<(NN + 3) / 4, 256, 0, stream>>>(bufA, offs, csr, dis, b1, bufB, NN);
  // layer 2
  k_gemm_scale<<<ggrid, 256, 0, stream>>>(bufB, W2, dis, bufA, NN);
  k_aggregate<<<(NN + 3) / 4, 256, 0, stream>>>(bufA, offs, csr, dis, b2, bufB, NN);
  // readout
  k_final<<<(NN + 3) / 4, 256, 0, stream>>>(bufB, Wl, bl, out, NN);
}